// Round 17
// baseline (358.740 us; speedup 1.0000x reference)
//
#include <hip/hip_runtime.h>
#include <utility>

// ---------------- constants ----------------
#define BATCH   2
#define SEQLEN  1024
#define DMODEL  512
#define DSTATE  32
#define DINNER  1024
#define MROWS   (BATCH*SEQLEN)          // 2048
#define NPROJ   (2*DINNER + 2*DINNER*DSTATE)  // 67584

typedef short bf16x8 __attribute__((ext_vector_type(8)));
typedef float f32x4  __attribute__((ext_vector_type(4)));

template <int... Is, class F>
__device__ __forceinline__ void static_for_impl(std::integer_sequence<int, Is...>, F&& f) {
    (f(std::integral_constant<int, Is>{}), ...);
}
template <int N, class F>
__device__ __forceinline__ void static_for(F&& f) {
    static_for_impl(std::make_integer_sequence<int, N>{}, static_cast<F&&>(f));
}

__device__ __forceinline__ unsigned short f2bf(float f) {
    union { float f; unsigned u; } c; c.f = f;
    unsigned u = c.u;
    u += 0x7fffu + ((u >> 16) & 1u);   // RTNE
    return (unsigned short)(u >> 16);
}
__device__ __forceinline__ float bf2f(unsigned short h) {
    union { unsigned u; float f; } c; c.u = ((unsigned)h) << 16;
    return c.f;
}

// ---------------- cast fp32 -> bf16 (weights concat + x + Wout) ----------------
__global__ void cast_all(const float4* __restrict__ Wx, const float4* __restrict__ Wdt,
                         const float4* __restrict__ WB, const float4* __restrict__ WC,
                         const float4* __restrict__ x,  const float4* __restrict__ Wout,
                         unsigned short* __restrict__ Wbf,
                         unsigned short* __restrict__ Xbf,
                         unsigned short* __restrict__ Woutbf) {
    const long nWx = 131072, nWdt = 131072, nWB = 4194304, nWC = 4194304;
    const long nWall = nWx + nWdt + nWB + nWC;      // 8650752
    const long nX = 262144, nWo = 131072;
    const long total = nWall + nX + nWo;            // 9043968
    for (long u = (long)blockIdx.x * blockDim.x + threadIdx.x; u < total;
         u += (long)gridDim.x * blockDim.x) {
        float4 v; unsigned short* dst;
        if (u < nWall) {
            if (u < nWx)             v = Wx[u];
            else if (u < nWx+nWdt)   v = Wdt[u - nWx];
            else if (u < nWx+nWdt+nWB) v = WB[u - nWx - nWdt];
            else                     v = WC[u - nWx - nWdt - nWB];
            dst = Wbf + u*4;
        } else if (u < nWall + nX) {
            v = x[u - nWall];       dst = Xbf + (u - nWall)*4;
        } else {
            v = Wout[u - nWall - nX]; dst = Woutbf + (u - nWall - nX)*4;
        }
        ushort4 o; o.x = f2bf(v.x); o.y = f2bf(v.y); o.z = f2bf(v.z); o.w = f2bf(v.w);
        *(ushort4*)dst = o;
    }
}

// ---------------- bf16 MFMA GEMM: C[rows,N] = A[rows,KCT] * Bw[N,KCT]^T ----------------
// 128x128 tile, BK=32, 4 waves (2x2). XCD band swizzle; static_for K-loop
// (constexpr addresses); bank-conflict-free LDS via pre-swizzled global source.
// R17: 3-buffer / ONE-barrier pipeline (48KB LDS, 3 blocks/CU):
//   iter it: vmcnt(4) [own tile-it loads drained]; s_barrier [all waves' data in
//   LDS; also fences buf[it%3]'s prior readers]; STAGE(it+2 -> buf[(it+2)%3]);
//   COMPUTE(it%3). 8 loads in flight through compute (2-deep prefetch); half
//   the barriers of the R13/R16 2-buffer form.
template<int EPI, int KCT>
__global__ __launch_bounds__(256)
void gemm_bt(const unsigned short* __restrict__ A, const unsigned short* __restrict__ Bw,
             int N, int t0, int Tchunk, int tgs,
             unsigned short* __restrict__ xinb, float* __restrict__ dlt,
             unsigned short* __restrict__ Bout, unsigned short* __restrict__ Cout,
             const float* __restrict__ bdt, float* __restrict__ outf) {
    __shared__ unsigned short Asm[3][128*32];
    __shared__ unsigned short Bsm[3][128*32];
    constexpr int K  = KCT;
    constexpr int nt = KCT >> 5;      // K/32 iterations
    const int tid  = threadIdx.x;
    const int w    = tid >> 6;
    const int lane = tid & 63;
    const int wm   = w >> 1, wn = w & 1;

    // ---- XCD band swizzle ----
    const int nx = gridDim.x, ny = gridDim.y;
    int ntile, rtile;
    if ((nx & 7) == 0) {
        const int lin = blockIdx.x + nx * blockIdx.y;
        const int xcd = lin & 7;
        const int sl  = lin >> 3;
        ntile = xcd * (nx >> 3) + sl / ny;
        rtile = sl % ny;
    } else {
        ntile = blockIdx.x; rtile = blockIdx.y;
    }

    const int rr0  = rtile * 128;                 // chunk-local row base of tile
    const int bb   = (rr0 >= Tchunk) ? 1 : 0;
    const int grow0 = bb * SEQLEN + t0 + (rr0 - bb * Tchunk);  // global row base
    const int n0   = ntile * 128;

    f32x4 acc[4][4] = {};

    const unsigned short* Ag = A  + (size_t)grow0 * K;
    const unsigned short* Bg = Bw + (size_t)n0 * K;

    const int c0 = w*64 + lane;       // LDS chunk ids (16B units)
    const int c1 = c0 + 256;
    const int r   = lane & 15;
    const int h16 = lane >> 4;

    // pre-swizzled global source base pointers (constexpr offsets fold per iter)
    const int rowc0 = c0 >> 2, rowc1 = c1 >> 2;
    const int subc0 = (c0 & 3) ^ ((c0 >> 3) & 3);
    const int subc1 = (c1 & 3) ^ ((c1 >> 3) & 3);
    typedef const __attribute__((address_space(1))) unsigned short gq_t;
    gq_t* agp0 = (gq_t*)(Ag + (size_t)rowc0 * K + subc0 * 8);
    gq_t* agp1 = (gq_t*)(Ag + (size_t)rowc1 * K + subc1 * 8);
    gq_t* bgp0 = (gq_t*)(Bg + (size_t)rowc0 * K + subc0 * 8);
    gq_t* bgp1 = (gq_t*)(Bg + (size_t)rowc1 * K + subc1 * 8);

    #define STAGE(koff_, buf_)                                                            \
        do {                                                                              \
            __builtin_amdgcn_global_load_lds((const __attribute__((address_space(1))) void*)(agp0 + (koff_)), \
                (__attribute__((address_space(3))) void*)(&Asm[(buf_)][w*512]), 16, 0, 0);\
            __builtin_amdgcn_global_load_lds((const __attribute__((address_space(1))) void*)(agp1 + (koff_)), \
                (__attribute__((address_space(3))) void*)(&Asm[(buf_)][2048 + w*512]), 16, 0, 0); \
            __builtin_amdgcn_global_load_lds((const __attribute__((address_space(1))) void*)(bgp0 + (koff_)), \
                (__attribute__((address_space(3))) void*)(&Bsm[(buf_)][w*512]), 16, 0, 0);\
            __builtin_amdgcn_global_load_lds((const __attribute__((address_space(1))) void*)(bgp1 + (koff_)), \
                (__attribute__((address_space(3))) void*)(&Bsm[(buf_)][2048 + w*512]), 16, 0, 0); \
        } while (0)

    #define COMPUTE(buf_)                                                                 \
        do {                                                                              \
            bf16x8 af[4], bfr[4];                                                         \
            _Pragma("unroll")                                                             \
            for (int i = 0; i < 4; i++) {                                                 \
                const int Ra = wm*64 + i*16 + r;                                          \
                const int Rb = wn*64 + i*16 + r;                                          \
                af[i]  = *(const bf16x8*)(&Asm[(buf_)][Ra*32 + (h16 ^ ((Ra>>1)&3))*8]);   \
                bfr[i] = *(const bf16x8*)(&Bsm[(buf_)][Rb*32 + (h16 ^ ((Rb>>1)&3))*8]);   \
            }                                                                             \
            _Pragma("unroll")                                                             \
            for (int i = 0; i < 4; i++)                                                   \
                _Pragma("unroll")                                                         \
                for (int j = 0; j < 4; j++)                                               \
                    acc[i][j] = __builtin_amdgcn_mfma_f32_16x16x32_bf16(af[i], bfr[j], acc[i][j], 0, 0, 0); \
        } while (0)

    STAGE(0, 0);
    STAGE(32, 1);
    static_for<nt>([&](auto itc) {
        constexpr int it  = decltype(itc)::value;
        constexpr int cur = it % 3;
        if constexpr (it + 1 < nt) {
            asm volatile("s_waitcnt vmcnt(4)" ::: "memory");   // own tile-it loads landed
        } else {
            asm volatile("s_waitcnt vmcnt(0)" ::: "memory");
        }
        __builtin_amdgcn_s_barrier();                          // all waves' tile-it in LDS
        asm volatile("" ::: "memory");
        if constexpr (it + 2 < nt) {
            STAGE((it + 2) * 32, (it + 2) % 3);                // write 2-ahead buffer
        }
        COMPUTE(cur);
        asm volatile("" ::: "memory");
    });

    #undef STAGE
    #undef COMPUTE

    // epilogue: C/D layout col=lane&15, row=(lane>>4)*4+reg
    const int q = lane >> 4;
    const int Tg  = 1 << tgs;
    const int NT  = Tg >> 3;
    #pragma unroll
    for (int i = 0; i < 4; i++) {
        const int lr0 = wm*64 + i*16 + q*4;      // local row base (4 consecutive rows)
        #pragma unroll
        for (int j = 0; j < 4; j++) {
            const int ncol = n0 + wn*64 + j*16 + r;
            if (EPI == 0) {
                const int cr   = rr0 + lr0;              // chunk-local row
                const int lt   = cr - bb*Tchunk;         // chunk-local t (first of 4)
                const int seg  = lt >> tgs;
                const int tloc = lt & (Tg - 1);
                const int kin  = tloc >> 3;
                const int tin  = tloc & 7;               // 0 or 4
                const int bs   = bb*8 + seg;             // [b][seg] fused index
                if (ncol < 1024) {
                    short4 o;
                    o.x = (short)f2bf(acc[i][j][0]); o.y = (short)f2bf(acc[i][j][1]);
                    o.z = (short)f2bf(acc[i][j][2]); o.w = (short)f2bf(acc[i][j][3]);
                    *(short4*)(xinb + ((size_t)bs*1024 + ncol)*Tg + tloc) = o;
                } else if (ncol < 2048) {
                    const float bias = bdt[ncol - 1024];
                    float4 o;
                    {   float z0 = acc[i][j][0] + bias; o.x = (z0 > 20.f) ? z0 : log1pf(__expf(z0));
                        float z1 = acc[i][j][1] + bias; o.y = (z1 > 20.f) ? z1 : log1pf(__expf(z1));
                        float z2 = acc[i][j][2] + bias; o.z = (z2 > 20.f) ? z2 : log1pf(__expf(z2));
                        float z3 = acc[i][j][3] + bias; o.w = (z3 > 20.f) ? z3 : log1pf(__expf(z3)); }
                    *(float4*)(dlt + ((size_t)bs*1024 + (ncol-1024))*Tg + tloc) = o;
                } else if (ncol < 34816) {
                    const int es = ncol - 2048;
                    short4 o;
                    o.x = (short)f2bf(acc[i][j][0]); o.y = (short)f2bf(acc[i][j][1]);
                    o.z = (short)f2bf(acc[i][j][2]); o.w = (short)f2bf(acc[i][j][3]);
                    *(short4*)(Bout + (((size_t)bs*1024 + (es>>5))*NT + kin)*256 + (es&31)*8 + tin) = o;
                } else {
                    const int es = ncol - 34816;
                    short4 o;
                    o.x = (short)f2bf(acc[i][j][0]); o.y = (short)f2bf(acc[i][j][1]);
                    o.z = (short)f2bf(acc[i][j][2]); o.w = (short)f2bf(acc[i][j][3]);
                    *(short4*)(Cout + (((size_t)bs*1024 + (es>>5))*NT + kin)*256 + (es&31)*8 + tin) = o;
                }
            } else {
                #pragma unroll
                for (int t = 0; t < 4; t++)
                    outf[(size_t)(grow0 + lr0 + t)*N + ncol] = acc[i][j][t];
            }
        }
    }
}

// ================= fused segmented scan (lean streaming, race-fixed) =================
// Block = one (b,e). 8 groups of 32 lanes = 8 segments x 32 states.
// hbuf carry is read BEFORE __syncthreads(), written by g==7 after (ordered).
template<int NT>
__global__ __launch_bounds__(256)
void scan_fused(const float* __restrict__ dlt, const unsigned short* __restrict__ xinb,
                const unsigned short* __restrict__ Bbf, const unsigned short* __restrict__ Cbf,
                const float* __restrict__ A_log,
                unsigned short* __restrict__ Ybf, float* __restrict__ hbuf,
                int t0, int first) {
    const int tid = threadIdx.x;
    const int g = tid >> 5, s = tid & 31;
    const int G = blockIdx.x;                // 0..2047 = (b,e)
    const int b = G >> 10, e = G & 1023;
    const int bs = b*8 + g;                  // [b][seg] fused index
    const int Tg = NT * 8;

    const float Aes = -__expf(A_log[e*32 + s]);

    const float*          dp = dlt  + ((size_t)bs*1024 + e)*Tg;
    const unsigned short* xp = xinb + ((size_t)bs*1024 + e)*Tg;
    const unsigned short* bp = Bbf  + ((size_t)bs*1024 + e)*NT*256 + s*8;
    const unsigned short* cp = Cbf  + ((size_t)bs*1024 + e)*NT*256 + s*8;

    // read previous-chunk carry BEFORE any barrier/write (race fix)
    const float hin0 = first ? 0.f : hbuf[(size_t)G*32 + s];

    // ---- phase 1: local scan (streaming) ----
    float h = 0.f, ap = 1.f;
    #pragma unroll 2
    for (int k = 0; k < NT; k++) {
        const bf16x8 bv = *(const bf16x8*)(bp + (size_t)k*256);
        const bf16x8 xv = *(const bf16x8*)(xp + k*8);
        const float4 d0 = *(const float4*)(dp + k*8), d1 = *(const float4*)(dp + k*8 + 4);
        const float db[8] = {d0.x,d0.y,d0.z,d0.w,d1.x,d1.y,d1.z,d1.w};
        #pragma unroll
        for (int j = 0; j < 8; j++) {
            const float a = __expf(db[j] * Aes);
            h = a*h + bf2f((unsigned short)bv[j])*bf2f((unsigned short)xv[j]);
            ap *= a;
        }
    }

    // ---- phase 2: segment prefix via LDS ----
    __shared__ float Lh[8][32];
    __shared__ float La[8][32];
    Lh[g][s] = h; La[g][s] = ap;
    __syncthreads();               // orders: all hbuf reads above, write below
    float hin = hin0;
    #pragma unroll
    for (int j = 0; j < 7; j++) {
        if (j < g) hin = La[j][s]*hin + Lh[j][s];
    }
    if (g == 7) hbuf[(size_t)G*32 + s] = La[7][s]*hin + Lh[7][s];   // carry out

    // ---- phase 3: re-scan with h_in, stream B+C, fold, emit y ----
    h = hin;
    const int tbase = t0 + g*Tg;
    #pragma unroll 2
    for (int k = 0; k < NT; k++) {
        const bf16x8 bv = *(const bf16x8*)(bp + (size_t)k*256);
        const bf16x8 cv = *(const bf16x8*)(cp + (size_t)k*256);
        const bf16x8 xv = *(const bf16x8*)(xp + k*8);
        const float4 d0 = *(const float4*)(dp + k*8), d1 = *(const float4*)(dp + k*8 + 4);
        const float db[8] = {d0.x,d0.y,d0.z,d0.w,d1.x,d1.y,d1.z,d1.w};
        float p[8];
        #pragma unroll
        for (int j = 0; j < 8; j++) {
            const float a = __expf(db[j] * Aes);
            h = a*h + bf2f((unsigned short)bv[j])*bf2f((unsigned short)xv[j]);
            p[j] = bf2f((unsigned short)cv[j])*h;
        }
        // butterfly fold: 8 t-values over 32 lanes
        #pragma unroll
        for (int i2 = 0; i2 < 4; i2++) {
            float send = (s & 16) ? p[i2] : p[i2+4];
            float recv = __shfl_xor(send, 16, 32);
            p[i2] = ((s & 16) ? p[i2+4] : p[i2]) + recv;
        }
        #pragma unroll
        for (int i2 = 0; i2 < 2; i2++) {
            float send = (s & 8) ? p[i2] : p[i2+2];
            float recv = __shfl_xor(send, 8, 32);
            p[i2] = ((s & 8) ? p[i2+2] : p[i2]) + recv;
        }
        {
            float send = (s & 4) ? p[0] : p[1];
            float recv = __shfl_xor(send, 4, 32);
            p[0] = ((s & 4) ? p[1] : p[0]) + recv;
        }
        p[0] += __shfl_xor(p[0], 2, 32);
        p[0] += __shfl_xor(p[0], 1, 32);
        if ((s & 3) == 0) {
            const int tl = s >> 2;
            const float qv = p[0];
            const float y = qv * __builtin_amdgcn_rcpf(1.f + __expf(-qv));  // SiLU
            Ybf[(size_t)b*1048576 + e + (size_t)(tbase + k*8 + tl)*1024] = f2bf(y);
        }
    }
}

// ---------------- launch ----------------
extern "C" void kernel_launch(void* const* d_in, const int* in_sizes, int n_in,
                              void* d_out, int out_size, void* d_ws, size_t ws_size,
                              hipStream_t stream) {
    const float* x     = (const float*)d_in[0];
    const float* Wx    = (const float*)d_in[1];
    const float* Wdt   = (const float*)d_in[2];
    const float* bdt   = (const float*)d_in[3];
    const float* A_log = (const float*)d_in[4];
    const float* WB    = (const float*)d_in[5];
    const float* WC    = (const float*)d_in[6];
    const float* Wout  = (const float*)d_in[7];

    // ---- workspace layout (fixed part = 89,391,104 B) ----
    char* ws = (char*)d_ws;
    unsigned short* Wbf    = (unsigned short*)(ws);                 // 69,206,016
    unsigned short* Xbf    = (unsigned short*)(ws + 69206016);      //  2,097,152
    unsigned short* Woutbf = (unsigned short*)(ws + 71303168);      //  1,048,576
    unsigned short* xinb   = (unsigned short*)(ws + 72351744);      //  4,194,304 (bf16)
    float*          dlt    = (float*)        (ws + 76546048);       //  8,388,608
    unsigned short* Ybf    = (unsigned short*)(ws + 84934656);      //  4,194,304
    float*          hbuf   = (float*)        (ws + 89128960);       //    262,144
    unsigned short* Bbf    = (unsigned short*)(ws + 89391104);      // T*131072 B each
    const size_t fixedB = 89391104;

    int T = 128;
    const int cands[4] = {1024, 512, 256, 128};
    for (int ci = 0; ci < 4; ci++) {
        if (fixedB + (size_t)2 * cands[ci] * 131072 <= ws_size) { T = cands[ci]; break; }
    }
    unsigned short* Cbf = Bbf + (size_t)T * 65536;

    const int Tg = T / 8;                 // power of 2
    int tgs = 0; while ((1 << tgs) < Tg) tgs++;
    const int NT = Tg / 8;                // 16/8/4/2

    cast_all<<<dim3(4096), dim3(256), 0, stream>>>(
        (const float4*)Wx, (const float4*)Wdt, (const float4*)WB, (const float4*)WC,
        (const float4*)x, (const float4*)Wout, Wbf, Xbf, Woutbf);

    const int NC = SEQLEN / T;
    for (int c = 0; c < NC; c++) {
        const int t0 = c * T;
        const int first = (c == 0) ? 1 : 0;
        gemm_bt<0, DMODEL><<<dim3(NPROJ/128, 2*T/128), dim3(256), 0, stream>>>(
            Xbf, Wbf, NPROJ, t0, T, tgs, xinb, dlt, Bbf, Cbf, bdt, nullptr);
        if (NT == 16)
            scan_fused<16><<<dim3(2048), dim3(256), 0, stream>>>(
                dlt, xinb, Bbf, Cbf, A_log, Ybf, hbuf, t0, first);
        else if (NT == 8)
            scan_fused<8><<<dim3(2048), dim3(256), 0, stream>>>(
                dlt, xinb, Bbf, Cbf, A_log, Ybf, hbuf, t0, first);
        else if (NT == 4)
            scan_fused<4><<<dim3(2048), dim3(256), 0, stream>>>(
                dlt, xinb, Bbf, Cbf, A_log, Ybf, hbuf, t0, first);
        else
            scan_fused<2><<<dim3(2048), dim3(256), 0, stream>>>(
                dlt, xinb, Bbf, Cbf, A_log, Ybf, hbuf, t0, first);
    }

    gemm_bt<1, DINNER><<<dim3(DMODEL/128, MROWS/128), dim3(256), 0, stream>>>(
        Ybf, Woutbf, DMODEL, 0, MROWS, 0, nullptr, nullptr, nullptr, nullptr, nullptr,
        (float*)d_out);
}

// Round 18
// 346.216 us; speedup vs baseline: 1.0362x; 1.0362x over previous
//
#include <hip/hip_runtime.h>
#include <utility>

// ---------------- constants ----------------
#define BATCH   2
#define SEQLEN  1024
#define DMODEL  512
#define DSTATE  32
#define DINNER  1024
#define MROWS   (BATCH*SEQLEN)          // 2048
#define NPROJ   (2*DINNER + 2*DINNER*DSTATE)  // 67584

typedef short bf16x8 __attribute__((ext_vector_type(8)));
typedef float f32x4  __attribute__((ext_vector_type(4)));

template <int... Is, class F>
__device__ __forceinline__ void static_for_impl(std::integer_sequence<int, Is...>, F&& f) {
    (f(std::integral_constant<int, Is>{}), ...);
}
template <int N, class F>
__device__ __forceinline__ void static_for(F&& f) {
    static_for_impl(std::make_integer_sequence<int, N>{}, static_cast<F&&>(f));
}

__device__ __forceinline__ unsigned short f2bf(float f) {
    union { float f; unsigned u; } c; c.f = f;
    unsigned u = c.u;
    u += 0x7fffu + ((u >> 16) & 1u);   // RTNE
    return (unsigned short)(u >> 16);
}
__device__ __forceinline__ float bf2f(unsigned short h) {
    union { unsigned u; float f; } c; c.u = ((unsigned)h) << 16;
    return c.f;
}

// ---------------- cast fp32 -> bf16 (weights concat + x + Wout) ----------------
__global__ void cast_all(const float4* __restrict__ Wx, const float4* __restrict__ Wdt,
                         const float4* __restrict__ WB, const float4* __restrict__ WC,
                         const float4* __restrict__ x,  const float4* __restrict__ Wout,
                         unsigned short* __restrict__ Wbf,
                         unsigned short* __restrict__ Xbf,
                         unsigned short* __restrict__ Woutbf) {
    const long nWx = 131072, nWdt = 131072, nWB = 4194304, nWC = 4194304;
    const long nWall = nWx + nWdt + nWB + nWC;      // 8650752
    const long nX = 262144, nWo = 131072;
    const long total = nWall + nX + nWo;            // 9043968
    for (long u = (long)blockIdx.x * blockDim.x + threadIdx.x; u < total;
         u += (long)gridDim.x * blockDim.x) {
        float4 v; unsigned short* dst;
        if (u < nWall) {
            if (u < nWx)             v = Wx[u];
            else if (u < nWx+nWdt)   v = Wdt[u - nWx];
            else if (u < nWx+nWdt+nWB) v = WB[u - nWx - nWdt];
            else                     v = WC[u - nWx - nWdt - nWB];
            dst = Wbf + u*4;
        } else if (u < nWall + nX) {
            v = x[u - nWall];       dst = Xbf + (u - nWall)*4;
        } else {
            v = Wout[u - nWall - nX]; dst = Woutbf + (u - nWall - nX)*4;
        }
        ushort4 o; o.x = f2bf(v.x); o.y = f2bf(v.y); o.z = f2bf(v.z); o.w = f2bf(v.w);
        *(ushort4*)dst = o;
    }
}

// ---------------- bf16 MFMA GEMM: C[rows,N] = A[rows,KCT] * Bw[N,KCT]^T ----------------
// R16-proven optimum of the 2-phase family at K=512:
// 128x128 tile, BK=32, 4 waves (2x2). XCD band swizzle; 2-deep double-buffer
// with counted vmcnt(4); static_for K-loop (constexpr addresses);
// bank-conflict-free LDS via pre-swizzled global source (slot' = slot ^ ((row>>1)&3)).
// Structure sweep R13-R17: BK=64 (-17%), 256^2 (-20%), 3-buf/1-barrier (-5%)
// all regress vs this config -> latency/concurrency-bound local optimum.
template<int EPI, int KCT>
__global__ __launch_bounds__(256)
void gemm_bt(const unsigned short* __restrict__ A, const unsigned short* __restrict__ Bw,
             int N, int t0, int Tchunk, int tgs,
             unsigned short* __restrict__ xinb, float* __restrict__ dlt,
             unsigned short* __restrict__ Bout, unsigned short* __restrict__ Cout,
             const float* __restrict__ bdt, float* __restrict__ outf) {
    __shared__ unsigned short Asm[2][128*32];
    __shared__ unsigned short Bsm[2][128*32];
    constexpr int K  = KCT;
    constexpr int nt = KCT >> 5;      // K/32 iterations
    const int tid  = threadIdx.x;
    const int w    = tid >> 6;
    const int lane = tid & 63;
    const int wm   = w >> 1, wn = w & 1;

    // ---- XCD band swizzle ----
    const int nx = gridDim.x, ny = gridDim.y;
    int ntile, rtile;
    if ((nx & 7) == 0) {
        const int lin = blockIdx.x + nx * blockIdx.y;
        const int xcd = lin & 7;
        const int sl  = lin >> 3;
        ntile = xcd * (nx >> 3) + sl / ny;
        rtile = sl % ny;
    } else {
        ntile = blockIdx.x; rtile = blockIdx.y;
    }

    const int rr0  = rtile * 128;                 // chunk-local row base of tile
    const int bb   = (rr0 >= Tchunk) ? 1 : 0;
    const int grow0 = bb * SEQLEN + t0 + (rr0 - bb * Tchunk);  // global row base
    const int n0   = ntile * 128;

    f32x4 acc[4][4] = {};

    const unsigned short* Ag = A  + (size_t)grow0 * K;
    const unsigned short* Bg = Bw + (size_t)n0 * K;

    const int c0 = w*64 + lane;       // LDS chunk ids (16B units)
    const int c1 = c0 + 256;
    const int r   = lane & 15;
    const int h16 = lane >> 4;

    // pre-swizzled global source base pointers (constexpr offsets fold per iter)
    const int rowc0 = c0 >> 2, rowc1 = c1 >> 2;
    const int subc0 = (c0 & 3) ^ ((c0 >> 3) & 3);
    const int subc1 = (c1 & 3) ^ ((c1 >> 3) & 3);
    typedef const __attribute__((address_space(1))) unsigned short gq_t;
    gq_t* agp0 = (gq_t*)(Ag + (size_t)rowc0 * K + subc0 * 8);
    gq_t* agp1 = (gq_t*)(Ag + (size_t)rowc1 * K + subc1 * 8);
    gq_t* bgp0 = (gq_t*)(Bg + (size_t)rowc0 * K + subc0 * 8);
    gq_t* bgp1 = (gq_t*)(Bg + (size_t)rowc1 * K + subc1 * 8);

    #define STAGE(koff_, buf_)                                                            \
        do {                                                                              \
            __builtin_amdgcn_global_load_lds((const __attribute__((address_space(1))) void*)(agp0 + (koff_)), \
                (__attribute__((address_space(3))) void*)(&Asm[(buf_)][w*512]), 16, 0, 0);\
            __builtin_amdgcn_global_load_lds((const __attribute__((address_space(1))) void*)(agp1 + (koff_)), \
                (__attribute__((address_space(3))) void*)(&Asm[(buf_)][2048 + w*512]), 16, 0, 0); \
            __builtin_amdgcn_global_load_lds((const __attribute__((address_space(1))) void*)(bgp0 + (koff_)), \
                (__attribute__((address_space(3))) void*)(&Bsm[(buf_)][w*512]), 16, 0, 0);\
            __builtin_amdgcn_global_load_lds((const __attribute__((address_space(1))) void*)(bgp1 + (koff_)), \
                (__attribute__((address_space(3))) void*)(&Bsm[(buf_)][2048 + w*512]), 16, 0, 0); \
        } while (0)

    #define COMPUTE(buf_)                                                                 \
        do {                                                                              \
            bf16x8 af[4], bfr[4];                                                         \
            _Pragma("unroll")                                                             \
            for (int i = 0; i < 4; i++) {                                                 \
                const int Ra = wm*64 + i*16 + r;                                          \
                const int Rb = wn*64 + i*16 + r;                                          \
                af[i]  = *(const bf16x8*)(&Asm[(buf_)][Ra*32 + (h16 ^ ((Ra>>1)&3))*8]);   \
                bfr[i] = *(const bf16x8*)(&Bsm[(buf_)][Rb*32 + (h16 ^ ((Rb>>1)&3))*8]);   \
            }                                                                             \
            _Pragma("unroll")                                                             \
            for (int i = 0; i < 4; i++)                                                   \
                _Pragma("unroll")                                                         \
                for (int j = 0; j < 4; j++)                                               \
                    acc[i][j] = __builtin_amdgcn_mfma_f32_16x16x32_bf16(af[i], bfr[j], acc[i][j], 0, 0, 0); \
        } while (0)

    STAGE(0, 0);
    static_for<nt - 1>([&](auto itc) {
        constexpr int it  = decltype(itc)::value;
        constexpr int cur = it & 1;
        STAGE((it + 1) * 32, cur ^ 1);                     // constexpr offset (shorts)
        asm volatile("s_waitcnt vmcnt(4)" ::: "memory");   // old 4 landed; new 4 in flight
        __builtin_amdgcn_s_barrier();
        COMPUTE(cur);
        asm volatile("" ::: "memory");
        __builtin_amdgcn_s_barrier();                      // protect buf cur before re-stage
        asm volatile("" ::: "memory");
    });
    asm volatile("s_waitcnt vmcnt(0)" ::: "memory");
    __builtin_amdgcn_s_barrier();
    {
        constexpr int last = (nt - 1) & 1;
        COMPUTE(last);
    }

    #undef STAGE
    #undef COMPUTE

    // epilogue: C/D layout col=lane&15, row=(lane>>4)*4+reg
    const int q = lane >> 4;
    const int Tg  = 1 << tgs;
    const int NT  = Tg >> 3;
    #pragma unroll
    for (int i = 0; i < 4; i++) {
        const int lr0 = wm*64 + i*16 + q*4;      // local row base (4 consecutive rows)
        #pragma unroll
        for (int j = 0; j < 4; j++) {
            const int ncol = n0 + wn*64 + j*16 + r;
            if (EPI == 0) {
                const int cr   = rr0 + lr0;              // chunk-local row
                const int lt   = cr - bb*Tchunk;         // chunk-local t (first of 4)
                const int seg  = lt >> tgs;
                const int tloc = lt & (Tg - 1);
                const int kin  = tloc >> 3;
                const int tin  = tloc & 7;               // 0 or 4
                const int bs   = bb*8 + seg;             // [b][seg] fused index
                if (ncol < 1024) {
                    short4 o;
                    o.x = (short)f2bf(acc[i][j][0]); o.y = (short)f2bf(acc[i][j][1]);
                    o.z = (short)f2bf(acc[i][j][2]); o.w = (short)f2bf(acc[i][j][3]);
                    *(short4*)(xinb + ((size_t)bs*1024 + ncol)*Tg + tloc) = o;
                } else if (ncol < 2048) {
                    const float bias = bdt[ncol - 1024];
                    float4 o;
                    {   float z0 = acc[i][j][0] + bias; o.x = (z0 > 20.f) ? z0 : log1pf(__expf(z0));
                        float z1 = acc[i][j][1] + bias; o.y = (z1 > 20.f) ? z1 : log1pf(__expf(z1));
                        float z2 = acc[i][j][2] + bias; o.z = (z2 > 20.f) ? z2 : log1pf(__expf(z2));
                        float z3 = acc[i][j][3] + bias; o.w = (z3 > 20.f) ? z3 : log1pf(__expf(z3)); }
                    *(float4*)(dlt + ((size_t)bs*1024 + (ncol-1024))*Tg + tloc) = o;
                } else if (ncol < 34816) {
                    const int es = ncol - 2048;
                    short4 o;
                    o.x = (short)f2bf(acc[i][j][0]); o.y = (short)f2bf(acc[i][j][1]);
                    o.z = (short)f2bf(acc[i][j][2]); o.w = (short)f2bf(acc[i][j][3]);
                    *(short4*)(Bout + (((size_t)bs*1024 + (es>>5))*NT + kin)*256 + (es&31)*8 + tin) = o;
                } else {
                    const int es = ncol - 34816;
                    short4 o;
                    o.x = (short)f2bf(acc[i][j][0]); o.y = (short)f2bf(acc[i][j][1]);
                    o.z = (short)f2bf(acc[i][j][2]); o.w = (short)f2bf(acc[i][j][3]);
                    *(short4*)(Cout + (((size_t)bs*1024 + (es>>5))*NT + kin)*256 + (es&31)*8 + tin) = o;
                }
            } else {
                #pragma unroll
                for (int t = 0; t < 4; t++)
                    outf[(size_t)(grow0 + lr0 + t)*N + ncol] = acc[i][j][t];
            }
        }
    }
}

// ================= fused segmented scan (lean streaming, race-fixed) =================
// Block = one (b,e). 8 groups of 32 lanes = 8 segments x 32 states.
// hbuf carry is read BEFORE __syncthreads(), written by g==7 after (ordered).
template<int NT>
__global__ __launch_bounds__(256)
void scan_fused(const float* __restrict__ dlt, const unsigned short* __restrict__ xinb,
                const unsigned short* __restrict__ Bbf, const unsigned short* __restrict__ Cbf,
                const float* __restrict__ A_log,
                unsigned short* __restrict__ Ybf, float* __restrict__ hbuf,
                int t0, int first) {
    const int tid = threadIdx.x;
    const int g = tid >> 5, s = tid & 31;
    const int G = blockIdx.x;                // 0..2047 = (b,e)
    const int b = G >> 10, e = G & 1023;
    const int bs = b*8 + g;                  // [b][seg] fused index
    const int Tg = NT * 8;

    const float Aes = -__expf(A_log[e*32 + s]);

    const float*          dp = dlt  + ((size_t)bs*1024 + e)*Tg;
    const unsigned short* xp = xinb + ((size_t)bs*1024 + e)*Tg;
    const unsigned short* bp = Bbf  + ((size_t)bs*1024 + e)*NT*256 + s*8;
    const unsigned short* cp = Cbf  + ((size_t)bs*1024 + e)*NT*256 + s*8;

    // read previous-chunk carry BEFORE any barrier/write (race fix)
    const float hin0 = first ? 0.f : hbuf[(size_t)G*32 + s];

    // ---- phase 1: local scan (streaming) ----
    float h = 0.f, ap = 1.f;
    #pragma unroll 2
    for (int k = 0; k < NT; k++) {
        const bf16x8 bv = *(const bf16x8*)(bp + (size_t)k*256);
        const bf16x8 xv = *(const bf16x8*)(xp + k*8);
        const float4 d0 = *(const float4*)(dp + k*8), d1 = *(const float4*)(dp + k*8 + 4);
        const float db[8] = {d0.x,d0.y,d0.z,d0.w,d1.x,d1.y,d1.z,d1.w};
        #pragma unroll
        for (int j = 0; j < 8; j++) {
            const float a = __expf(db[j] * Aes);
            h = a*h + bf2f((unsigned short)bv[j])*bf2f((unsigned short)xv[j]);
            ap *= a;
        }
    }

    // ---- phase 2: segment prefix via LDS ----
    __shared__ float Lh[8][32];
    __shared__ float La[8][32];
    Lh[g][s] = h; La[g][s] = ap;
    __syncthreads();               // orders: all hbuf reads above, write below
    float hin = hin0;
    #pragma unroll
    for (int j = 0; j < 7; j++) {
        if (j < g) hin = La[j][s]*hin + Lh[j][s];
    }
    if (g == 7) hbuf[(size_t)G*32 + s] = La[7][s]*hin + Lh[7][s];   // carry out

    // ---- phase 3: re-scan with h_in, stream B+C, fold, emit y ----
    h = hin;
    const int tbase = t0 + g*Tg;
    #pragma unroll 2
    for (int k = 0; k < NT; k++) {
        const bf16x8 bv = *(const bf16x8*)(bp + (size_t)k*256);
        const bf16x8 cv = *(const bf16x8*)(cp + (size_t)k*256);
        const bf16x8 xv = *(const bf16x8*)(xp + k*8);
        const float4 d0 = *(const float4*)(dp + k*8), d1 = *(const float4*)(dp + k*8 + 4);
        const float db[8] = {d0.x,d0.y,d0.z,d0.w,d1.x,d1.y,d1.z,d1.w};
        float p[8];
        #pragma unroll
        for (int j = 0; j < 8; j++) {
            const float a = __expf(db[j] * Aes);
            h = a*h + bf2f((unsigned short)bv[j])*bf2f((unsigned short)xv[j]);
            p[j] = bf2f((unsigned short)cv[j])*h;
        }
        // butterfly fold: 8 t-values over 32 lanes
        #pragma unroll
        for (int i2 = 0; i2 < 4; i2++) {
            float send = (s & 16) ? p[i2] : p[i2+4];
            float recv = __shfl_xor(send, 16, 32);
            p[i2] = ((s & 16) ? p[i2+4] : p[i2]) + recv;
        }
        #pragma unroll
        for (int i2 = 0; i2 < 2; i2++) {
            float send = (s & 8) ? p[i2] : p[i2+2];
            float recv = __shfl_xor(send, 8, 32);
            p[i2] = ((s & 8) ? p[i2+2] : p[i2]) + recv;
        }
        {
            float send = (s & 4) ? p[0] : p[1];
            float recv = __shfl_xor(send, 4, 32);
            p[0] = ((s & 4) ? p[1] : p[0]) + recv;
        }
        p[0] += __shfl_xor(p[0], 2, 32);
        p[0] += __shfl_xor(p[0], 1, 32);
        if ((s & 3) == 0) {
            const int tl = s >> 2;
            const float qv = p[0];
            const float y = qv * __builtin_amdgcn_rcpf(1.f + __expf(-qv));  // SiLU
            Ybf[(size_t)b*1048576 + e + (size_t)(tbase + k*8 + tl)*1024] = f2bf(y);
        }
    }
}

// ---------------- launch ----------------
extern "C" void kernel_launch(void* const* d_in, const int* in_sizes, int n_in,
                              void* d_out, int out_size, void* d_ws, size_t ws_size,
                              hipStream_t stream) {
    const float* x     = (const float*)d_in[0];
    const float* Wx    = (const float*)d_in[1];
    const float* Wdt   = (const float*)d_in[2];
    const float* bdt   = (const float*)d_in[3];
    const float* A_log = (const float*)d_in[4];
    const float* WB    = (const float*)d_in[5];
    const float* WC    = (const float*)d_in[6];
    const float* Wout  = (const float*)d_in[7];

    // ---- workspace layout (fixed part = 89,391,104 B) ----
    char* ws = (char*)d_ws;
    unsigned short* Wbf    = (unsigned short*)(ws);                 // 69,206,016
    unsigned short* Xbf    = (unsigned short*)(ws + 69206016);      //  2,097,152
    unsigned short* Woutbf = (unsigned short*)(ws + 71303168);      //  1,048,576
    unsigned short* xinb   = (unsigned short*)(ws + 72351744);      //  4,194,304 (bf16)
    float*          dlt    = (float*)        (ws + 76546048);       //  8,388,608
    unsigned short* Ybf    = (unsigned short*)(ws + 84934656);      //  4,194,304
    float*          hbuf   = (float*)        (ws + 89128960);       //    262,144
    unsigned short* Bbf    = (unsigned short*)(ws + 89391104);      // T*131072 B each
    const size_t fixedB = 89391104;

    int T = 128;
    const int cands[4] = {1024, 512, 256, 128};
    for (int ci = 0; ci < 4; ci++) {
        if (fixedB + (size_t)2 * cands[ci] * 131072 <= ws_size) { T = cands[ci]; break; }
    }
    unsigned short* Cbf = Bbf + (size_t)T * 65536;

    const int Tg = T / 8;                 // power of 2
    int tgs = 0; while ((1 << tgs) < Tg) tgs++;
    const int NT = Tg / 8;                // 16/8/4/2

    cast_all<<<dim3(4096), dim3(256), 0, stream>>>(
        (const float4*)Wx, (const float4*)Wdt, (const float4*)WB, (const float4*)WC,
        (const float4*)x, (const float4*)Wout, Wbf, Xbf, Woutbf);

    const int NC = SEQLEN / T;
    for (int c = 0; c < NC; c++) {
        const int t0 = c * T;
        const int first = (c == 0) ? 1 : 0;
        gemm_bt<0, DMODEL><<<dim3(NPROJ/128, 2*T/128), dim3(256), 0, stream>>>(
            Xbf, Wbf, NPROJ, t0, T, tgs, xinb, dlt, Bbf, Cbf, bdt, nullptr);
        if (NT == 16)
            scan_fused<16><<<dim3(2048), dim3(256), 0, stream>>>(
                dlt, xinb, Bbf, Cbf, A_log, Ybf, hbuf, t0, first);
        else if (NT == 8)
            scan_fused<8><<<dim3(2048), dim3(256), 0, stream>>>(
                dlt, xinb, Bbf, Cbf, A_log, Ybf, hbuf, t0, first);
        else if (NT == 4)
            scan_fused<4><<<dim3(2048), dim3(256), 0, stream>>>(
                dlt, xinb, Bbf, Cbf, A_log, Ybf, hbuf, t0, first);
        else
            scan_fused<2><<<dim3(2048), dim3(256), 0, stream>>>(
                dlt, xinb, Bbf, Cbf, A_log, Ybf, hbuf, t0, first);
    }

    gemm_bt<1, DINNER><<<dim3(DMODEL/128, MROWS/128), dim3(256), 0, stream>>>(
        Ybf, Woutbf, DMODEL, 0, MROWS, 0, nullptr, nullptr, nullptr, nullptr, nullptr,
        (float*)d_out);
}